// Round 4
// baseline (461.637 us; speedup 1.0000x reference)
//
#include <hip/hip_runtime.h>
#include <cstdint>
#include <cstddef>

#define BN 4
#define CC 27
#define HH 160
#define WW 160
#define HWp (HH*WW)        // 25600
#define NPIX (BN*HWp)      // 102400
#define DD 768
#define KK 24
#define NSPLIT 80
#define SPX (HWp/NSPLIT)   // 320 px per split
#define NCH (SPX/64)       // 5 chunks of 64 px

// ---- workspace float offsets ----
#define OFF_ACC 0                        // 32 scalars
#define OFF_S1 32                        // B*K*C = 2592
#define OFF_S2 (OFF_S1+2592)
#define OFF_CNT (OFF_S2+2592)            // 96
#define OFF_PP (OFF_CNT+96)              // B*CC*DD = 82944
#define OFF_QP (OFF_PP+82944)
#define OFF_NSQ (OFF_QP+82944)           // NPIX (atomically accumulated)
#define ZERO_N (OFF_NSQ+NPIX)            // zeroed each call
#define OFF_LAB ZERO_N                   // uint8 labels, NPIX bytes = NPIX/4 floats
#define OFF_PROBS (OFF_LAB + NPIX/4)     // BN*CC*HWp fp32
#define OFF_FBF (OFF_PROBS + BN*CC*HWp)  // bf16 feats linear [b][d][n]
#define OFF_WBF (OFF_FBF + (size_t)BN*DD*HWp/2)  // bf16 W linear [b][64][n]

// acc slots: 0 gsum, 1 distill, 2 bplnum, 3 bplcnt, 4 ent, 5 alignH, 6 alignV,
//            7 bceH(vert), 8 bceW(horiz), 9 proto

typedef __attribute__((ext_vector_type(8))) short short8v;
typedef __attribute__((ext_vector_type(4))) float f32x4;

__device__ __forceinline__ float wave_sum(float v) {
#pragma unroll
  for (int o = 32; o > 0; o >>= 1) v += __shfl_down(v, o, 64);
  return v;
}

__device__ __forceinline__ unsigned short f2bf(float x) {
  unsigned u = __builtin_bit_cast(unsigned, x);
  unsigned r = u + 0x7FFFu + ((u >> 16) & 1u);
  return (unsigned short)(r >> 16);
}

__global__ void k_zero(float* __restrict__ w, int n) {
  int i = blockIdx.x * 256 + threadIdx.x;
  if (i < n) w[i] = 0.f;
}

__global__ void k_depth_stats(const float* __restrict__ depth, float* __restrict__ acc) {
  int i = blockIdx.x * 256 + threadIdx.x;
  float g = 0.f;
  if (i < NPIX) {
    int b = i / HWp, r = i % HWp, h = r / WW, w = r % WW;
    const float* dp = depth + b * HWp;
    float d0 = dp[r];
    float gh = (h < HH-1) ? fabsf(dp[r+WW] - d0) : 0.f;
    float gw = (w < WW-1) ? fabsf(dp[r+1] - d0) : 0.f;
    g = gh + gw;
  }
  __shared__ float red;
  if (threadIdx.x == 0) red = 0.f;
  __syncthreads();
  float s = wave_sum(g);
  if ((threadIdx.x & 63) == 0) atomicAdd(&red, s);
  __syncthreads();
  if (threadIdx.x == 0) atomicAdd(&acc[0], red);
}

__global__ void k_labels(const float* __restrict__ cl, unsigned char* __restrict__ lab) {
  int i = blockIdx.x * 256 + threadIdx.x;
  if (i >= NPIX) return;
  int b = i / HWp, r = i % HWp;
  const float* p = cl + (size_t)b * CC * HWp + r;
  float best = p[0]; int bi = 0;
#pragma unroll
  for (int c = 1; c < CC; ++c) {
    float v = p[(size_t)c * HWp];
    if (v > best) { best = v; bi = c; }
  }
  lab[i] = (unsigned char)bi;
}

// fp32 feats -> bf16 linear fbf[b][d][n], plus per-pixel norm^2 (8 partial atomics/px)
__global__ void __launch_bounds__(256) k_fconv(const float* __restrict__ feats,
        unsigned short* __restrict__ fbf, float* __restrict__ nsq) {
  int t = threadIdx.x;
  int slab = blockIdx.x;                 // 200 slabs of 512 px
  int b = slab / (HWp / 512);
  int px0 = (slab % (HWp / 512)) * 512;
  int d0 = blockIdx.y * (DD / 8);        // 8-way d split, 96 rows each
  int p = px0 + 2 * t;
  const float* src = feats + ((size_t)b * DD + d0) * HWp + p;
  unsigned short* dst = fbf + ((size_t)b * DD + d0) * HWp + p;
  float n0 = 0.f, n1 = 0.f;
#pragma unroll 4
  for (int d = 0; d < DD / 8; ++d) {
    float2 v = *(const float2*)(src + (size_t)d * HWp);
    n0 += v.x * v.x; n1 += v.y * v.y;
    ushort2 h; h.x = f2bf(v.x); h.y = f2bf(v.y);
    *(ushort2*)(dst + (size_t)d * HWp) = h;
  }
  atomicAdd(&nsq[b * HWp + p], n0);
  atomicAdd(&nsq[b * HWp + p + 1], n1);
}

// per-pixel: softmax stats + distill/bpl/entropy scalars, probs fp32,
// and W rows: wbf[c]=bf16(pt), wbf[32+c]=bf16(pt*invnorm)
__global__ void k_main(const float* __restrict__ logits, const float* __restrict__ depth,
                       const unsigned char* __restrict__ lab, const float* __restrict__ nsq,
                       float* __restrict__ probs, unsigned short* __restrict__ wbf,
                       float* __restrict__ acc) {
  int i = blockIdx.x * 256 + threadIdx.x;
  float c_dist = 0.f, c_bnum = 0.f, c_bcnt = 0.f, c_ent = 0.f;
  if (i < NPIX) {
    int b = i / HWp, r = i % HWp, h = r / WW, w = r % WW;
    const float* lg = logits + (size_t)b * CC * HWp + r;
    float x[CC];
    float m = -1e30f;
#pragma unroll
    for (int c = 0; c < CC; ++c) { x[c] = lg[(size_t)c * HWp]; m = fmaxf(m, x[c]); }
    float se = 0.f, sx = 0.f, set = 0.f;
#pragma unroll
    for (int c = 0; c < CC; ++c) {
      se += expf(x[c] - m);
      set += expf(10.f * (x[c] - m));
      sx += x[c];
    }
    float lse = logf(se);
    float inv_set = 1.f / set;
    float invn = 1.f / fmaxf(sqrtf(nsq[i]), 1e-12f);
    int l = lab[i];
    float xl = x[0];
    float ent = 0.f;
    float* pb = probs + (size_t)b * CC * HWp + r;
    unsigned short* wb = wbf + (size_t)b * 64 * HWp + r;
#pragma unroll
    for (int c = 0; c < CC; ++c) {
      float lp = x[c] - m - lse;
      float p = expf(lp);
      pb[(size_t)c * HWp] = p;
      float ptc = expf(10.f * (x[c] - m)) * inv_set;
      wb[(size_t)c * HWp] = f2bf(ptc);
      wb[(size_t)(32 + c) * HWp] = f2bf(ptc * invn);
      ent -= p * lp;
      if (c == l) xl = x[c];
    }
    float nll = m + lse - xl;
    float ce = 0.8f * nll + 0.2f * (m + lse - sx * (1.f / CC));
    float ptf = expf(-ce);
    float wgt = (1.f - ptf) * (1.f - ptf);
    if (l >= 11 && l <= 18) wgt *= 2.f;
    const float* dp = depth + b * HWp;
    float d0 = dp[r];
    float gh = (h < HH-1) ? fabsf(dp[r+WW] - d0) : 0.f;
    float gw = (w < WW-1) ? fabsf(dp[r+1] - d0) : 0.f;
    float gmean = acc[0] * (1.f / NPIX);
    float gnorm = (gh + gw) / (gmean + 1e-6f);
    wgt *= 1.f + 0.1f * fminf(gnorm, 3.f);
    const unsigned char* lb = lab + b * HWp;
    int lL = lb[h*WW + (w>0 ? w-1 : w)];
    int lR = lb[h*WW + (w<WW-1 ? w+1 : w)];
    int lU = lb[(h>0 ? h-1 : h)*WW + w];
    int lD = lb[(h<HH-1 ? h+1 : h)*WW + w];
    float bnd = ((l != lL) | (l != lR) | (l != lU) | (l != lD)) ? 1.f : 0.f;
    c_dist = ce * wgt;
    c_bnum = ce * bnd;
    c_bcnt = bnd;
    c_ent = ent;
  }
  __shared__ float red[4];
  if (threadIdx.x < 4) red[threadIdx.x] = 0.f;
  __syncthreads();
  c_dist = wave_sum(c_dist); c_bnum = wave_sum(c_bnum);
  c_bcnt = wave_sum(c_bcnt); c_ent = wave_sum(c_ent);
  if ((threadIdx.x & 63) == 0) {
    atomicAdd(&red[0], c_dist); atomicAdd(&red[1], c_bnum);
    atomicAdd(&red[2], c_bcnt); atomicAdd(&red[3], c_ent);
  }
  __syncthreads();
  if (threadIdx.x == 0) {
    atomicAdd(&acc[1], red[0]); atomicAdd(&acc[2], red[1]);
    atomicAdd(&acc[3], red[2]); atomicAdd(&acc[4], red[3]);
  }
}

// MFMA GEMM v4: no LDS, no barriers. Register-direct fragments from linear
// bf16 arrays. Per block (b, dt, s): [128 d x 64 c'] over 320 px.
__global__ void __launch_bounds__(256) k_gemm(const unsigned short* __restrict__ fbf,
        const unsigned short* __restrict__ wbf,
        float* __restrict__ P, float* __restrict__ Q) {
  int bx = blockIdx.x;
  int s  = bx % NSPLIT;
  int dt = (bx / NSPLIT) % 6;
  int b  = bx / (NSPLIT * 6);
  int t = threadIdx.x;
  int wave = t >> 6, lane = t & 63;
  int g = lane >> 4, rr = lane & 15;
  f32x4 acc[2][4] = {};
  int n0 = s * SPX;
  const unsigned short* A0 = fbf + ((size_t)b * DD + dt * 128) * HWp + n0 + g * 8;
  const unsigned short* W0 = wbf + (size_t)b * 64 * HWp + n0 + g * 8;
  const unsigned short* Ar0 = A0 + (size_t)((wave * 2 + 0) * 16 + rr) * HWp;
  const unsigned short* Ar1 = A0 + (size_t)((wave * 2 + 1) * 16 + rr) * HWp;
  const unsigned short* Wr0 = W0 + (size_t)(0 * 16 + rr) * HWp;
  const unsigned short* Wr1 = W0 + (size_t)(1 * 16 + rr) * HWp;
  const unsigned short* Wr2 = W0 + (size_t)(2 * 16 + rr) * HWp;
  const unsigned short* Wr3 = W0 + (size_t)(3 * 16 + rr) * HWp;
#pragma unroll 1
  for (int ch = 0; ch < NCH; ++ch) {
    int off = ch * 64;
#pragma unroll
    for (int ks = 0; ks < 2; ++ks) {
      int o = off + ks * 32;
      short8v a0 = *(const short8v*)(Ar0 + o);
      short8v a1 = *(const short8v*)(Ar1 + o);
      short8v w0 = *(const short8v*)(Wr0 + o);
      short8v w1 = *(const short8v*)(Wr1 + o);
      short8v w2 = *(const short8v*)(Wr2 + o);
      short8v w3 = *(const short8v*)(Wr3 + o);
      acc[0][0] = __builtin_amdgcn_mfma_f32_16x16x32_bf16(a0, w0, acc[0][0], 0, 0, 0);
      acc[0][1] = __builtin_amdgcn_mfma_f32_16x16x32_bf16(a0, w1, acc[0][1], 0, 0, 0);
      acc[0][2] = __builtin_amdgcn_mfma_f32_16x16x32_bf16(a0, w2, acc[0][2], 0, 0, 0);
      acc[0][3] = __builtin_amdgcn_mfma_f32_16x16x32_bf16(a0, w3, acc[0][3], 0, 0, 0);
      acc[1][0] = __builtin_amdgcn_mfma_f32_16x16x32_bf16(a1, w0, acc[1][0], 0, 0, 0);
      acc[1][1] = __builtin_amdgcn_mfma_f32_16x16x32_bf16(a1, w1, acc[1][1], 0, 0, 0);
      acc[1][2] = __builtin_amdgcn_mfma_f32_16x16x32_bf16(a1, w2, acc[1][2], 0, 0, 0);
      acc[1][3] = __builtin_amdgcn_mfma_f32_16x16x32_bf16(a1, w3, acc[1][3], 0, 0, 0);
    }
  }
  // epilogue: C/D layout col=lane&15 (c'), row=(lane>>4)*4+reg (d)
#pragma unroll
  for (int dd = 0; dd < 2; ++dd) {
#pragma unroll
    for (int ct = 0; ct < 4; ++ct) {
      int cp = ct * 16 + rr;
#pragma unroll
      for (int rg = 0; rg < 4; ++rg) {
        int d = dt * 128 + (wave * 2 + dd) * 16 + g * 4 + rg;
        float v = acc[dd][ct][rg];
        if (cp < CC)
          atomicAdd(&P[((size_t)b * CC + cp) * DD + d], v);
        else if (cp >= 32 && cp < 32 + CC)
          atomicAdd(&Q[((size_t)b * CC + (cp - 32)) * DD + d], v);
      }
    }
  }
}

__global__ void k_align_ib(const float* __restrict__ probs, const float* __restrict__ depth,
                           const int* __restrict__ inst, float* __restrict__ acc) {
  int i = blockIdx.x * 256 + threadIdx.x;
  float aH = 0.f, aV = 0.f, bh = 0.f, bw = 0.f;
  if (i < NPIX) {
    int b = i / HWp, r = i % HWp, h = r / WW, w = r % WW;
    const float* P = probs + (size_t)b * CC * HWp + r;
    bool hasR = (w < WW-1), hasD = (h < HH-1);
    float sh = 0.f, sv = 0.f, mh = 0.f, mw = 0.f;
#pragma unroll
    for (int c = 0; c < CC; ++c) {
      float p  = P[(size_t)c * HWp];
      float pr = hasR ? P[(size_t)c * HWp + 1]  : p;
      float pd = hasD ? P[(size_t)c * HWp + WW] : p;
      float dr = pr - p, dd = pd - p;
      sh += dr * dr; sv += dd * dd;
      mw = fmaxf(mw, fabsf(dr)); mh = fmaxf(mh, fabsf(dd));
    }
    const float* dp = depth + b * HWp;
    const int* ip = inst + b * HWp;
    float d0 = dp[r];
    if (hasR) {
      float ddh = dp[r+1] - d0;
      aH = expf(-(ddh*ddh) * 200.f) * sh;
      float y = (ip[r+1] != ip[r]) ? 1.f : 0.f;
      float xx = fminf(fmaxf(mw, 1e-6f), 1.f - 1e-6f);
      bw = -(y * logf(xx) + (1.f - y) * log1pf(-xx));
    }
    if (hasD) {
      float ddv = dp[r+WW] - d0;
      aV = expf(-(ddv*ddv) * 200.f) * sv;
      float y = (ip[r+WW] != ip[r]) ? 1.f : 0.f;
      float xx = fminf(fmaxf(mh, 1e-6f), 1.f - 1e-6f);
      bh = -(y * logf(xx) + (1.f - y) * log1pf(-xx));
    }
  }
  __shared__ float red[4];
  if (threadIdx.x < 4) red[threadIdx.x] = 0.f;
  __syncthreads();
  aH = wave_sum(aH); aV = wave_sum(aV); bh = wave_sum(bh); bw = wave_sum(bw);
  if ((threadIdx.x & 63) == 0) {
    atomicAdd(&red[0], aH); atomicAdd(&red[1], aV);
    atomicAdd(&red[2], bh); atomicAdd(&red[3], bw);
  }
  __syncthreads();
  if (threadIdx.x == 0) {
    atomicAdd(&acc[5], red[0]); atomicAdd(&acc[6], red[1]);
    atomicAdd(&acc[7], red[2]); atomicAdd(&acc[8], red[3]);
  }
}

__global__ void k_iu(const float* __restrict__ probs, const int* __restrict__ inst,
                     float* __restrict__ s1g, float* __restrict__ s2g, float* __restrict__ cntg) {
  __shared__ float ls1[4][KK*CC], ls2[4][KK*CC], lc[4][KK];
  int t = threadIdx.x; int w = t >> 6;
  for (int idx = t; idx < 4*KK*CC; idx += 256) { (&ls1[0][0])[idx] = 0.f; (&ls2[0][0])[idx] = 0.f; }
  if (t < 4*KK) (&lc[0][0])[t] = 0.f;
  __syncthreads();
  int b = blockIdx.x / (HWp / 512);
  int seg = blockIdx.x % (HWp / 512);
  int base = seg * 512;
#pragma unroll
  for (int q = 0; q < 2; ++q) {
    int n = base + q * 256 + t;
    int id = inst[b * HWp + n];
    const float* Pp = probs + (size_t)b * CC * HWp + n;
    atomicAdd(&lc[w][id], 1.f);
#pragma unroll
    for (int c = 0; c < CC; ++c) {
      float p = Pp[(size_t)c * HWp];
      atomicAdd(&ls1[w][id*CC + c], p);
      atomicAdd(&ls2[w][id*CC + c], p * p);
    }
  }
  __syncthreads();
  for (int idx = t; idx < KK*CC; idx += 256) {
    atomicAdd(&s1g[b*KK*CC + idx], ls1[0][idx]+ls1[1][idx]+ls1[2][idx]+ls1[3][idx]);
    atomicAdd(&s2g[b*KK*CC + idx], ls2[0][idx]+ls2[1][idx]+ls2[2][idx]+ls2[3][idx]);
  }
  if (t < KK) atomicAdd(&cntg[b*KK + t], lc[0][t]+lc[1][t]+lc[2][t]+lc[3][t]);
}

__global__ void k_pfinal(const float* __restrict__ P, const float* __restrict__ Q,
                         float* __restrict__ acc) {
  int bc = blockIdx.x;   // b*CC + c
  float dot = 0.f, nsq = 0.f;
  for (int d = threadIdx.x; d < DD; d += 256) {
    float p = P[(size_t)bc * DD + d];
    float q = Q[(size_t)bc * DD + d];
    dot += p * q; nsq += p * p;
  }
  __shared__ float red[2];
  if (threadIdx.x < 2) red[threadIdx.x] = 0.f;
  __syncthreads();
  dot = wave_sum(dot); nsq = wave_sum(nsq);
  if ((threadIdx.x & 63) == 0) { atomicAdd(&red[0], dot); atomicAdd(&red[1], nsq); }
  __syncthreads();
  if (threadIdx.x == 0) atomicAdd(&acc[9], red[0] / fmaxf(sqrtf(red[1]), 1e-12f));
}

__global__ void k_final(const float* __restrict__ s1g, const float* __restrict__ s2g,
                        const float* __restrict__ cntg, const float* __restrict__ acc,
                        float* __restrict__ out) {
  int t = threadIdx.x;
  float vsum = 0.f, vcnt = 0.f;
  if (t < BN*KK) {
    int k = t % KK;
    float count = cntg[t];
    float nc = fmaxf(count, 1.f);
    float var = 0.f;
#pragma unroll
    for (int c = 0; c < CC; ++c) {
      float m1 = s1g[t*CC + c] / nc;
      var += s2g[t*CC + c] / nc - m1 * m1;
    }
    var *= (1.f / CC);
    if (k > 0 && count >= 25.f) { vsum = var; vcnt = 1.f; }
  }
  __shared__ float red[2];
  if (t < 2) red[t] = 0.f;
  __syncthreads();
  vsum = wave_sum(vsum); vcnt = wave_sum(vcnt);
  if ((t & 63) == 0) { atomicAdd(&red[0], vsum); atomicAdd(&red[1], vcnt); }
  __syncthreads();
  if (t == 0) {
    float l_distill = acc[1] * (1.f / NPIX);
    float bcnt = acc[3];
    float l_bpl = (bcnt > 0.f) ? acc[2] / fmaxf(bcnt, 1.f) : 0.f;
    float l_align = acc[5] * (1.f / (BN*HH*(WW-1))) + acc[6] * (1.f / (BN*(HH-1)*WW));
    float l_ent = acc[4] * (1.f / NPIX);
    float l_ib = 0.5f * (acc[7] * (1.f / (BN*(HH-1)*WW)) + acc[8] * (1.f / (BN*HH*(WW-1))));
    float l_proto = -acc[9] * (1.f / NPIX);
    float l_iu = red[0] / fmaxf(red[1], 1.f);
    out[0] = 1.0f*l_distill + 0.5f*l_bpl + 5.0f*l_align + 0.5f*l_proto +
             0.3f*l_ent + 0.5f*l_iu + 0.5f*l_ib;
  }
}

extern "C" void kernel_launch(void* const* d_in, const int* in_sizes, int n_in,
                              void* d_out, int out_size, void* d_ws, size_t ws_size,
                              hipStream_t stream) {
  (void)in_sizes; (void)n_in; (void)out_size; (void)ws_size;
  const float* logits = (const float*)d_in[0];
  const float* cause  = (const float*)d_in[1];
  const float* feats  = (const float*)d_in[2];
  const float* depth  = (const float*)d_in[3];
  const int*   inst   = (const int*)d_in[4];
  float* ws = (float*)d_ws;
  float* acc = ws + OFF_ACC;
  float* s1  = ws + OFF_S1;
  float* s2  = ws + OFF_S2;
  float* cnt = ws + OFF_CNT;
  float* Pg  = ws + OFF_PP;
  float* Qg  = ws + OFF_QP;
  float* nsq = ws + OFF_NSQ;
  unsigned char* lab = (unsigned char*)(ws + OFF_LAB);
  float* probs = ws + OFF_PROBS;
  unsigned short* fbf = (unsigned short*)(ws + OFF_FBF);
  unsigned short* wbf = (unsigned short*)(ws + OFF_WBF);
  float* out = (float*)d_out;

  k_zero<<<(ZERO_N + 255) / 256, 256, 0, stream>>>(ws, ZERO_N);
  k_depth_stats<<<NPIX / 256, 256, 0, stream>>>(depth, acc);
  k_labels<<<NPIX / 256, 256, 0, stream>>>(cause, lab);
  k_fconv<<<dim3(NPIX / 512, 8), 256, 0, stream>>>(feats, fbf, nsq);
  k_main<<<NPIX / 256, 256, 0, stream>>>(logits, depth, lab, nsq, probs, wbf, acc);
  k_gemm<<<BN * 6 * NSPLIT, 256, 0, stream>>>(fbf, wbf, Pg, Qg);
  k_align_ib<<<NPIX / 256, 256, 0, stream>>>(probs, depth, inst, acc);
  k_iu<<<BN * (HWp / 512), 256, 0, stream>>>(probs, inst, s1, s2, cnt);
  k_pfinal<<<BN * CC, 256, 0, stream>>>(Pg, Qg, acc);
  k_final<<<1, 256, 0, stream>>>(s1, s2, cnt, acc, out);
}

// Round 5
// 338.275 us; speedup vs baseline: 1.3647x; 1.3647x over previous
//
#include <hip/hip_runtime.h>
#include <cstdint>
#include <cstddef>

#define BN 4
#define CC 27
#define HH 160
#define WW 160
#define HWp (HH*WW)        // 25600
#define NPIX (BN*HWp)      // 102400
#define DD 768
#define KK 24
#define NSPLIT 40
#define NCH 10             // 10 tiles of 64 px per split (640 px)
#define NT 400             // 64-px tiles per batch image

// ---- workspace float offsets ----
#define OFF_ACC 0                        // 32 scalars
#define OFF_S1 32                        // B*K*C = 2592
#define OFF_S2 (OFF_S1+2592)
#define OFF_CNT (OFF_S2+2592)            // 96
#define OFF_PP (OFF_CNT+96)              // B*CC*DD = 82944
#define OFF_QP (OFF_PP+82944)
#define OFF_NSQ (OFF_QP+82944)           // NPIX (atomically accumulated)
#define ZERO_N (OFF_NSQ+NPIX)            // zeroed each call
#define OFF_LAB ZERO_N                   // uint8 labels, NPIX bytes = NPIX/4 floats
#define OFF_PROBS (OFF_LAB + NPIX/4)     // BN*CC*HWp fp32
#define OFF_FBF (OFF_PROBS + BN*CC*HWp)  // bf16 feats TILED: (b,dt,T)[128][64] swizzled
#define OFF_WBF (OFF_FBF + (size_t)BN*6*NT*8192/2)  // bf16 W TILED: (b,T)[64][64] swizzled

// acc slots: 0 gsum, 1 distill, 2 bplnum, 3 bplcnt, 4 ent, 5 alignH, 6 alignV,
//            7 bceH(vert), 8 bceW(horiz), 9 proto

typedef __attribute__((ext_vector_type(8))) short short8v;
typedef __attribute__((ext_vector_type(4))) float f32x4;

__device__ __forceinline__ float wave_sum(float v) {
#pragma unroll
  for (int o = 32; o > 0; o >>= 1) v += __shfl_down(v, o, 64);
  return v;
}

__device__ __forceinline__ unsigned short f2bf(float x) {
  unsigned u = __builtin_bit_cast(unsigned, x);
  unsigned r = u + 0x7FFFu + ((u >> 16) & 1u);
  return (unsigned short)(r >> 16);
}

__global__ void k_zero(float* __restrict__ w, int n) {
  int i = blockIdx.x * 256 + threadIdx.x;
  if (i < n) w[i] = 0.f;
}

__global__ void k_depth_stats(const float* __restrict__ depth, float* __restrict__ acc) {
  int i = blockIdx.x * 256 + threadIdx.x;
  float g = 0.f;
  if (i < NPIX) {
    int b = i / HWp, r = i % HWp, h = r / WW, w = r % WW;
    const float* dp = depth + b * HWp;
    float d0 = dp[r];
    float gh = (h < HH-1) ? fabsf(dp[r+WW] - d0) : 0.f;
    float gw = (w < WW-1) ? fabsf(dp[r+1] - d0) : 0.f;
    g = gh + gw;
  }
  __shared__ float red;
  if (threadIdx.x == 0) red = 0.f;
  __syncthreads();
  float s = wave_sum(g);
  if ((threadIdx.x & 63) == 0) atomicAdd(&red, s);
  __syncthreads();
  if (threadIdx.x == 0) atomicAdd(&acc[0], red);
}

__global__ void k_labels(const float* __restrict__ cl, unsigned char* __restrict__ lab) {
  int i = blockIdx.x * 256 + threadIdx.x;
  if (i >= NPIX) return;
  int b = i / HWp, r = i % HWp;
  const float* p = cl + (size_t)b * CC * HWp + r;
  float best = p[0]; int bi = 0;
#pragma unroll
  for (int c = 1; c < CC; ++c) {
    float v = p[(size_t)c * HWp];
    if (v > best) { best = v; bi = c; }
  }
  lab[i] = (unsigned char)bi;
}

// fp32 feats -> bf16 TILED/SWIZZLED fbf, plus per-pixel norm^2 (8 partial atomics/px)
__global__ void __launch_bounds__(256) k_fconv(const float* __restrict__ feats,
        unsigned short* __restrict__ fbf, float* __restrict__ nsq) {
  int t = threadIdx.x;
  int slab = blockIdx.x;                 // 200 slabs of 512 px
  int b = slab / (HWp / 512);
  int px0 = (slab % (HWp / 512)) * 512;
  int d0 = blockIdx.y * (DD / 8);        // 8-way d split, 96 rows each
  int p = px0 + 2 * t;
  int T = p >> 6, j = p & 63;
  const float* src = feats + ((size_t)b * DD + d0) * HWp + p;
  float n0 = 0.f, n1 = 0.f;
#pragma unroll 4
  for (int d = 0; d < DD / 8; ++d) {
    int dgl = d0 + d;
    float2 v = *(const float2*)(src + (size_t)d * HWp);
    n0 += v.x * v.x; n1 += v.y * v.y;
    ushort2 h; h.x = f2bf(v.x); h.y = f2bf(v.y);
    int dt = dgl >> 7, rin = dgl & 127;
    size_t addr = ((size_t)(b * 6 + dt) * NT + T) * 8192 + rin * 64
                + (((j >> 3) ^ (rin & 7)) * 8) + (j & 7);
    *(ushort2*)&fbf[addr] = h;
  }
  atomicAdd(&nsq[b * HWp + p], n0);
  atomicAdd(&nsq[b * HWp + p + 1], n1);
}

// per-pixel: softmax stats + distill/bpl/entropy scalars, probs fp32,
// and W tiles (swizzled): row c = bf16(pt), row 32+c = bf16(pt*invnorm)
__global__ void k_main(const float* __restrict__ logits, const float* __restrict__ depth,
                       const unsigned char* __restrict__ lab, const float* __restrict__ nsq,
                       float* __restrict__ probs, unsigned short* __restrict__ wbf,
                       float* __restrict__ acc) {
  int i = blockIdx.x * 256 + threadIdx.x;
  float c_dist = 0.f, c_bnum = 0.f, c_bcnt = 0.f, c_ent = 0.f;
  if (i < NPIX) {
    int b = i / HWp, r = i % HWp, h = r / WW, w = r % WW;
    const float* lg = logits + (size_t)b * CC * HWp + r;
    float x[CC];
    float m = -1e30f;
#pragma unroll
    for (int c = 0; c < CC; ++c) { x[c] = lg[(size_t)c * HWp]; m = fmaxf(m, x[c]); }
    float se = 0.f, sx = 0.f, set = 0.f;
#pragma unroll
    for (int c = 0; c < CC; ++c) {
      se += expf(x[c] - m);
      set += expf(10.f * (x[c] - m));
      sx += x[c];
    }
    float lse = logf(se);
    float inv_set = 1.f / set;
    float invn = 1.f / fmaxf(sqrtf(nsq[i]), 1e-12f);
    int l = lab[i];
    float xl = x[0];
    float ent = 0.f;
    float* pb = probs + (size_t)b * CC * HWp + r;
    int T = r >> 6, j = r & 63;
    unsigned short* wb = wbf + ((size_t)b * NT + T) * 4096;
#pragma unroll
    for (int c = 0; c < CC; ++c) {
      float lp = x[c] - m - lse;
      float p = expf(lp);
      pb[(size_t)c * HWp] = p;
      float ptc = expf(10.f * (x[c] - m)) * inv_set;
      wb[c * 64 + (((j >> 3) ^ (c & 7)) * 8) + (j & 7)] = f2bf(ptc);
      int c2 = 32 + c;
      wb[c2 * 64 + (((j >> 3) ^ (c2 & 7)) * 8) + (j & 7)] = f2bf(ptc * invn);
      ent -= p * lp;
      if (c == l) xl = x[c];
    }
    float nll = m + lse - xl;
    float ce = 0.8f * nll + 0.2f * (m + lse - sx * (1.f / CC));
    float ptf = expf(-ce);
    float wgt = (1.f - ptf) * (1.f - ptf);
    if (l >= 11 && l <= 18) wgt *= 2.f;
    const float* dp = depth + b * HWp;
    float d0 = dp[r];
    float gh = (h < HH-1) ? fabsf(dp[r+WW] - d0) : 0.f;
    float gw = (w < WW-1) ? fabsf(dp[r+1] - d0) : 0.f;
    float gmean = acc[0] * (1.f / NPIX);
    float gnorm = (gh + gw) / (gmean + 1e-6f);
    wgt *= 1.f + 0.1f * fminf(gnorm, 3.f);
    const unsigned char* lb = lab + b * HWp;
    int lL = lb[h*WW + (w>0 ? w-1 : w)];
    int lR = lb[h*WW + (w<WW-1 ? w+1 : w)];
    int lU = lb[(h>0 ? h-1 : h)*WW + w];
    int lD = lb[(h<HH-1 ? h+1 : h)*WW + w];
    float bnd = ((l != lL) | (l != lR) | (l != lU) | (l != lD)) ? 1.f : 0.f;
    c_dist = ce * wgt;
    c_bnum = ce * bnd;
    c_bcnt = bnd;
    c_ent = ent;
  }
  __shared__ float red[4];
  if (threadIdx.x < 4) red[threadIdx.x] = 0.f;
  __syncthreads();
  c_dist = wave_sum(c_dist); c_bnum = wave_sum(c_bnum);
  c_bcnt = wave_sum(c_bcnt); c_ent = wave_sum(c_ent);
  if ((threadIdx.x & 63) == 0) {
    atomicAdd(&red[0], c_dist); atomicAdd(&red[1], c_bnum);
    atomicAdd(&red[2], c_bcnt); atomicAdd(&red[3], c_ent);
  }
  __syncthreads();
  if (threadIdx.x == 0) {
    atomicAdd(&acc[1], red[0]); atomicAdd(&acc[2], red[1]);
    atomicAdd(&acc[3], red[2]); atomicAdd(&acc[4], red[3]);
  }
}

// MFMA GEMM (r3 DMA structure): per block (b, dt, s) computes [128 d x 64 c']
// over 640 px, staging via global_load_lds DMA from pre-swizzled tiles,
// double-buffered LDS, counted vmcnt(6) + raw barriers. fp32 atomic finalize.
__global__ void __launch_bounds__(256) k_gemm(const unsigned short* __restrict__ fbf,
        const unsigned short* __restrict__ wbf, float* __restrict__ P, float* __restrict__ Q) {
  __shared__ unsigned short As[2][8192];
  __shared__ unsigned short Ws[2][4096];
  int bx = blockIdx.x;
  int s  = bx % NSPLIT;
  int dt = (bx / NSPLIT) % 6;
  int b  = bx / (NSPLIT * 6);
  int t = threadIdx.x;
  int wave = t >> 6, lane = t & 63;
  int g = lane >> 4, rr = lane & 15;
  f32x4 acc[2][4] = {};
  const unsigned short* Abase = fbf + ((size_t)(b*6+dt)*NT + s*NCH) * 8192;
  const unsigned short* Wbase = wbf + ((size_t)b*NT + s*NCH) * 4096;

#define STAGE(ch, bufi) do { \
    const unsigned short* as_ = Abase + (size_t)(ch) * 8192; \
    const unsigned short* ws_ = Wbase + (size_t)(ch) * 4096; \
    _Pragma("unroll") \
    for (int i_ = 0; i_ < 4; ++i_) { \
      int off_ = (wave*4 + i_) * 512; \
      __builtin_amdgcn_global_load_lds( \
        (const __attribute__((address_space(1))) void*)(as_ + off_ + lane*8), \
        (__attribute__((address_space(3))) void*)&As[bufi][off_], 16, 0, 0); \
    } \
    _Pragma("unroll") \
    for (int i_ = 0; i_ < 2; ++i_) { \
      int off_ = (wave*2 + i_) * 512; \
      __builtin_amdgcn_global_load_lds( \
        (const __attribute__((address_space(1))) void*)(ws_ + off_ + lane*8), \
        (__attribute__((address_space(3))) void*)&Ws[bufi][off_], 16, 0, 0); \
    } \
  } while (0)

  STAGE(0, 0);
  for (int ch = 0; ch < NCH; ++ch) {
    int cur = ch & 1;
    if (ch + 1 < NCH) {
      STAGE(ch + 1, cur ^ 1);
      asm volatile("s_waitcnt vmcnt(6)" ::: "memory");
    } else {
      asm volatile("s_waitcnt vmcnt(0)" ::: "memory");
    }
    __builtin_amdgcn_s_barrier();
    __builtin_amdgcn_sched_barrier(0);
#pragma unroll
    for (int ks = 0; ks < 2; ++ks) {
      short8v a[2], wf[4];
#pragma unroll
      for (int dd = 0; dd < 2; ++dd) {
        int row = (wave*2 + dd)*16 + rr;
        int ck = (ks*4 + g) ^ (row & 7);
        a[dd] = *(const short8v*)&As[cur][row*64 + ck*8];
      }
#pragma unroll
      for (int ct = 0; ct < 4; ++ct) {
        int row = ct*16 + rr;
        int ck = (ks*4 + g) ^ (row & 7);
        wf[ct] = *(const short8v*)&Ws[cur][row*64 + ck*8];
      }
#pragma unroll
      for (int dd = 0; dd < 2; ++dd)
#pragma unroll
        for (int ct = 0; ct < 4; ++ct)
          acc[dd][ct] = __builtin_amdgcn_mfma_f32_16x16x32_bf16(a[dd], wf[ct], acc[dd][ct], 0, 0, 0);
    }
    __builtin_amdgcn_sched_barrier(0);
    __builtin_amdgcn_s_barrier();
  }
#undef STAGE
  // epilogue: C/D layout col=lane&15 (c'), row=(lane>>4)*4+reg (d)
#pragma unroll
  for (int dd = 0; dd < 2; ++dd) {
#pragma unroll
    for (int ct = 0; ct < 4; ++ct) {
      int cp = ct * 16 + rr;
#pragma unroll
      for (int rg = 0; rg < 4; ++rg) {
        int d = dt * 128 + (wave * 2 + dd) * 16 + g * 4 + rg;
        float v = acc[dd][ct][rg];
        if (cp < CC)
          atomicAdd(&P[((size_t)b * CC + cp) * DD + d], v);
        else if (cp >= 32 && cp < 32 + CC)
          atomicAdd(&Q[((size_t)b * CC + (cp - 32)) * DD + d], v);
      }
    }
  }
}

__global__ void k_align_ib(const float* __restrict__ probs, const float* __restrict__ depth,
                           const int* __restrict__ inst, float* __restrict__ acc) {
  int i = blockIdx.x * 256 + threadIdx.x;
  float aH = 0.f, aV = 0.f, bh = 0.f, bw = 0.f;
  if (i < NPIX) {
    int b = i / HWp, r = i % HWp, h = r / WW, w = r % WW;
    const float* P = probs + (size_t)b * CC * HWp + r;
    bool hasR = (w < WW-1), hasD = (h < HH-1);
    float sh = 0.f, sv = 0.f, mh = 0.f, mw = 0.f;
#pragma unroll
    for (int c = 0; c < CC; ++c) {
      float p  = P[(size_t)c * HWp];
      float pr = hasR ? P[(size_t)c * HWp + 1]  : p;
      float pd = hasD ? P[(size_t)c * HWp + WW] : p;
      float dr = pr - p, dd = pd - p;
      sh += dr * dr; sv += dd * dd;
      mw = fmaxf(mw, fabsf(dr)); mh = fmaxf(mh, fabsf(dd));
    }
    const float* dp = depth + b * HWp;
    const int* ip = inst + b * HWp;
    float d0 = dp[r];
    if (hasR) {
      float ddh = dp[r+1] - d0;
      aH = expf(-(ddh*ddh) * 200.f) * sh;
      float y = (ip[r+1] != ip[r]) ? 1.f : 0.f;
      float xx = fminf(fmaxf(mw, 1e-6f), 1.f - 1e-6f);
      bw = -(y * logf(xx) + (1.f - y) * log1pf(-xx));
    }
    if (hasD) {
      float ddv = dp[r+WW] - d0;
      aV = expf(-(ddv*ddv) * 200.f) * sv;
      float y = (ip[r+WW] != ip[r]) ? 1.f : 0.f;
      float xx = fminf(fmaxf(mh, 1e-6f), 1.f - 1e-6f);
      bh = -(y * logf(xx) + (1.f - y) * log1pf(-xx));
    }
  }
  __shared__ float red[4];
  if (threadIdx.x < 4) red[threadIdx.x] = 0.f;
  __syncthreads();
  aH = wave_sum(aH); aV = wave_sum(aV); bh = wave_sum(bh); bw = wave_sum(bw);
  if ((threadIdx.x & 63) == 0) {
    atomicAdd(&red[0], aH); atomicAdd(&red[1], aV);
    atomicAdd(&red[2], bh); atomicAdd(&red[3], bw);
  }
  __syncthreads();
  if (threadIdx.x == 0) {
    atomicAdd(&acc[5], red[0]); atomicAdd(&acc[6], red[1]);
    atomicAdd(&acc[7], red[2]); atomicAdd(&acc[8], red[3]);
  }
}

__global__ void k_iu(const float* __restrict__ probs, const int* __restrict__ inst,
                     float* __restrict__ s1g, float* __restrict__ s2g, float* __restrict__ cntg) {
  __shared__ float ls1[4][KK*CC], ls2[4][KK*CC], lc[4][KK];
  int t = threadIdx.x; int w = t >> 6;
  for (int idx = t; idx < 4*KK*CC; idx += 256) { (&ls1[0][0])[idx] = 0.f; (&ls2[0][0])[idx] = 0.f; }
  if (t < 4*KK) (&lc[0][0])[t] = 0.f;
  __syncthreads();
  int b = blockIdx.x / (HWp / 512);
  int seg = blockIdx.x % (HWp / 512);
  int base = seg * 512;
#pragma unroll
  for (int q = 0; q < 2; ++q) {
    int n = base + q * 256 + t;
    int id = inst[b * HWp + n];
    const float* Pp = probs + (size_t)b * CC * HWp + n;
    atomicAdd(&lc[w][id], 1.f);
#pragma unroll
    for (int c = 0; c < CC; ++c) {
      float p = Pp[(size_t)c * HWp];
      atomicAdd(&ls1[w][id*CC + c], p);
      atomicAdd(&ls2[w][id*CC + c], p * p);
    }
  }
  __syncthreads();
  for (int idx = t; idx < KK*CC; idx += 256) {
    atomicAdd(&s1g[b*KK*CC + idx], ls1[0][idx]+ls1[1][idx]+ls1[2][idx]+ls1[3][idx]);
    atomicAdd(&s2g[b*KK*CC + idx], ls2[0][idx]+ls2[1][idx]+ls2[2][idx]+ls2[3][idx]);
  }
  if (t < KK) atomicAdd(&cntg[b*KK + t], lc[0][t]+lc[1][t]+lc[2][t]+lc[3][t]);
}

__global__ void k_pfinal(const float* __restrict__ P, const float* __restrict__ Q,
                         float* __restrict__ acc) {
  int bc = blockIdx.x;   // b*CC + c
  float dot = 0.f, nsq = 0.f;
  for (int d = threadIdx.x; d < DD; d += 256) {
    float p = P[(size_t)bc * DD + d];
    float q = Q[(size_t)bc * DD + d];
    dot += p * q; nsq += p * p;
  }
  __shared__ float red[2];
  if (threadIdx.x < 2) red[threadIdx.x] = 0.f;
  __syncthreads();
  dot = wave_sum(dot); nsq = wave_sum(nsq);
  if ((threadIdx.x & 63) == 0) { atomicAdd(&red[0], dot); atomicAdd(&red[1], nsq); }
  __syncthreads();
  if (threadIdx.x == 0) atomicAdd(&acc[9], red[0] / fmaxf(sqrtf(red[1]), 1e-12f));
}

__global__ void k_final(const float* __restrict__ s1g, const float* __restrict__ s2g,
                        const float* __restrict__ cntg, const float* __restrict__ acc,
                        float* __restrict__ out) {
  int t = threadIdx.x;
  float vsum = 0.f, vcnt = 0.f;
  if (t < BN*KK) {
    int k = t % KK;
    float count = cntg[t];
    float nc = fmaxf(count, 1.f);
    float var = 0.f;
#pragma unroll
    for (int c = 0; c < CC; ++c) {
      float m1 = s1g[t*CC + c] / nc;
      var += s2g[t*CC + c] / nc - m1 * m1;
    }
    var *= (1.f / CC);
    if (k > 0 && count >= 25.f) { vsum = var; vcnt = 1.f; }
  }
  __shared__ float red[2];
  if (t < 2) red[t] = 0.f;
  __syncthreads();
  vsum = wave_sum(vsum); vcnt = wave_sum(vcnt);
  if ((t & 63) == 0) { atomicAdd(&red[0], vsum); atomicAdd(&red[1], vcnt); }
  __syncthreads();
  if (t == 0) {
    float l_distill = acc[1] * (1.f / NPIX);
    float bcnt = acc[3];
    float l_bpl = (bcnt > 0.f) ? acc[2] / fmaxf(bcnt, 1.f) : 0.f;
    float l_align = acc[5] * (1.f / (BN*HH*(WW-1))) + acc[6] * (1.f / (BN*(HH-1)*WW));
    float l_ent = acc[4] * (1.f / NPIX);
    float l_ib = 0.5f * (acc[7] * (1.f / (BN*(HH-1)*WW)) + acc[8] * (1.f / (BN*HH*(WW-1))));
    float l_proto = -acc[9] * (1.f / NPIX);
    float l_iu = red[0] / fmaxf(red[1], 1.f);
    out[0] = 1.0f*l_distill + 0.5f*l_bpl + 5.0f*l_align + 0.5f*l_proto +
             0.3f*l_ent + 0.5f*l_iu + 0.5f*l_ib;
  }
}

extern "C" void kernel_launch(void* const* d_in, const int* in_sizes, int n_in,
                              void* d_out, int out_size, void* d_ws, size_t ws_size,
                              hipStream_t stream) {
  (void)in_sizes; (void)n_in; (void)out_size; (void)ws_size;
  const float* logits = (const float*)d_in[0];
  const float* cause  = (const float*)d_in[1];
  const float* feats  = (const float*)d_in[2];
  const float* depth  = (const float*)d_in[3];
  const int*   inst   = (const int*)d_in[4];
  float* ws = (float*)d_ws;
  float* acc = ws + OFF_ACC;
  float* s1  = ws + OFF_S1;
  float* s2  = ws + OFF_S2;
  float* cnt = ws + OFF_CNT;
  float* Pg  = ws + OFF_PP;
  float* Qg  = ws + OFF_QP;
  float* nsq = ws + OFF_NSQ;
  unsigned char* lab = (unsigned char*)(ws + OFF_LAB);
  float* probs = ws + OFF_PROBS;
  unsigned short* fbf = (unsigned short*)(ws + OFF_FBF);
  unsigned short* wbf = (unsigned short*)(ws + OFF_WBF);
  float* out = (float*)d_out;

  k_zero<<<(ZERO_N + 255) / 256, 256, 0, stream>>>(ws, ZERO_N);
  k_depth_stats<<<NPIX / 256, 256, 0, stream>>>(depth, acc);
  k_labels<<<NPIX / 256, 256, 0, stream>>>(cause, lab);
  k_fconv<<<dim3(NPIX / 512, 8), 256, 0, stream>>>(feats, fbf, nsq);
  k_main<<<NPIX / 256, 256, 0, stream>>>(logits, depth, lab, nsq, probs, wbf, acc);
  k_gemm<<<BN * 6 * NSPLIT, 256, 0, stream>>>(fbf, wbf, Pg, Qg);
  k_align_ib<<<NPIX / 256, 256, 0, stream>>>(probs, depth, inst, acc);
  k_iu<<<BN * (HWp / 512), 256, 0, stream>>>(probs, inst, s1, s2, cnt);
  k_pfinal<<<BN * CC, 256, 0, stream>>>(Pg, Qg, acc);
  k_final<<<1, 256, 0, stream>>>(s1, s2, cnt, acc, out);
}